// Round 1
// baseline (857.862 us; speedup 1.0000x reference)
//
#include <hip/hip_runtime.h>

// Problem constants (match reference)
#define N_NODES 40000
#define ISIZE   64
#define KNN     24
#define NE      (N_NODES * KNN)      // 960000 edges (= E_ADJ as well)
#define OMEGA   0.9f
#define HSIZE_LOG 21
#define HSIZE   (1u << HSIZE_LOG)    // 2097152 slots
#define HMASK   (HSIZE - 1u)

__device__ __forceinline__ unsigned hash_key(int key) {
    unsigned x = (unsigned)key;
    x *= 2654435761u;
    x ^= x >> 15;
    return x & HMASK;
}

// ---- degree count over adj_col -------------------------------------------
__global__ void k_degcount(const int* __restrict__ col, int* __restrict__ cnt) {
    int e = blockIdx.x * 256 + threadIdx.x;
    if (e < NE) atomicAdd(&cnt[col[e]], 1);
}

__global__ void k_dinv(const int* __restrict__ cnt, float* __restrict__ dinv) {
    int n = blockIdx.x * 256 + threadIdx.x;
    if (n < N_NODES) dinv[n] = rsqrtf(1.0f + (float)cnt[n]);
}

// ---- Y = X @ W  (N x 64) * (64 x 64) -------------------------------------
// 32 rows per block, W staged in LDS.
__global__ void k_gemm(const float* __restrict__ X, const float* __restrict__ W,
                       float* __restrict__ Y) {
    __shared__ float sW[64 * 64];
    __shared__ float sX[32 * 64];
    int row0 = blockIdx.x * 32;
    for (int t = threadIdx.x; t < 64 * 64; t += 256) sW[t] = W[t];
    for (int t = threadIdx.x; t < 32 * 64; t += 256) sX[t] = X[row0 * 64 + t];
    __syncthreads();
    int col = threadIdx.x & 63;
    int rl  = threadIdx.x >> 6;           // 0..3
    for (int r = rl; r < 32; r += 4) {
        float acc = 0.0f;
#pragma unroll
        for (int kk = 0; kk < 64; kk++) acc += sX[r * 64 + kk] * sW[kk * 64 + col];
        Y[(row0 + r) * 64 + col] = acc;
    }
}

// ---- edge aggregation: out[col] += dinv[row]*dinv[col] * xw[row] ---------
__global__ void k_agg(const float* __restrict__ xw, float* __restrict__ out,
                      const int* __restrict__ row, const int* __restrict__ col,
                      const float* __restrict__ dinv) {
    int t = blockIdx.x * 256 + threadIdx.x;   // NE*64 threads
    int e = t >> 6;
    int f = t & 63;
    int r = row[e], c = col[e];
    float coef = dinv[r] * dinv[c];
    atomicAdd(&out[c * 64 + f], coef * xw[r * 64 + f]);
}

// ---- finalize layer 1: B = relu(B + dinv^2 * A + b1) ---------------------
__global__ void k_fin1(float* __restrict__ B, const float* __restrict__ A,
                       const float* __restrict__ dinv, const float* __restrict__ bias) {
    int t = blockIdx.x * 256 + threadIdx.x;   // N*64 threads
    int n = t >> 6;
    int f = t & 63;
    float di = dinv[n];
    float v = B[t] + di * di * A[t] + bias[f];
    B[t] = fmaxf(v, 0.0f);
}

// ---- finalize layer 2 + row L2-normalize: C = normalize(C + dinv^2*A + b2)
__global__ void k_fin2norm(float* __restrict__ C, const float* __restrict__ A,
                           const float* __restrict__ dinv, const float* __restrict__ bias) {
    int t = blockIdx.x * 256 + threadIdx.x;   // N*64 threads; one wave per row
    int n = t >> 6;
    int f = t & 63;
    float di = dinv[n];
    float val = C[t] + di * di * A[t] + bias[f];
    float v2 = val * val;
#pragma unroll
    for (int m = 1; m < 64; m <<= 1) v2 += __shfl_xor(v2, m);
    float norm = sqrtf(v2);
    C[t] = val / fmaxf(norm, 1e-12f);
}

// ---- per-edge score + hash insert ----------------------------------------
// 16 lanes per edge, float4 loads over the 64-dim rows.
__global__ void k_edge(const float* __restrict__ h, const float* __restrict__ s_d,
                       const int* __restrict__ i_idx, const int* __restrict__ j_idx,
                       float* __restrict__ sval,
                       int* __restrict__ hkeys, int* __restrict__ hvals) {
    int t = blockIdx.x * 256 + threadIdx.x;   // NE*16 threads
    int e = t >> 4;
    int q = t & 15;
    int i = i_idx[e], j = j_idx[e];
    const float4* h4 = (const float4*)h;
    float4 a = h4[i * 16 + q];
    float4 b = h4[j * 16 + q];
    float s = a.x * b.x + a.y * b.y + a.z * b.z + a.w * b.w;
#pragma unroll
    for (int m = 1; m < 16; m <<= 1) s += __shfl_xor(s, m);
    if (q == 0) {
        float v = OMEGA * fmaxf(s, 0.0f) + (1.0f - OMEGA) * s_d[e];
        sval[e] = v;
        // hash insert: key -> min edge index
        int key = i * N_NODES + j;            // fits int32
        unsigned slot = hash_key(key);
        while (true) {
            int old = atomicCAS(&hkeys[slot], -1, key);
            if (old == -1 || old == key) { atomicMin(&hvals[slot], e); break; }
            slot = (slot + 1u) & HMASK;
        }
    }
}

// ---- symmetrize: lookup reverse edge, write vals_s, accumulate degree ----
__global__ void k_sym(const float* __restrict__ sval,
                      const int* __restrict__ i_idx, const int* __restrict__ j_idx,
                      const int* __restrict__ hkeys, const int* __restrict__ hvals,
                      float* __restrict__ outS,     // d_out + 2E, holds vals_s [2E]
                      float* __restrict__ deg2) {
    int e = blockIdx.x * 256 + threadIdx.x;   // NE threads
    int i = i_idx[e], j = j_idx[e];
    int rkey = j * N_NODES + i;
    unsigned slot = hash_key(rkey);
    int rev = -1;
    while (true) {
        int k = hkeys[slot];
        if (k == -1) break;
        if (k == rkey) { rev = hvals[slot]; break; }
        slot = (slot + 1u) & HMASK;
    }
    float v = sval[e];
    bool found = (rev >= 0);
    if (found) v = 0.5f * (v + sval[rev]);
    float v2 = found ? 0.0f : v;
    outS[e] = v;
    outS[NE + e] = v2;
    atomicAdd(&deg2[i], v);
    atomicAdd(&deg2[j], v2);
}

__global__ void k_dinv2(const float* __restrict__ deg2, float* __restrict__ dinv2) {
    int n = blockIdx.x * 256 + threadIdx.x;
    if (n < N_NODES) {
        float d = deg2[n];
        dinv2[n] = (d > 0.0f) ? rsqrtf(fmaxf(d, 1e-12f)) : 0.0f;
    }
}

// ---- final normalization: vals_norm = dinv2[r] * vals_s * dinv2[c] -------
__global__ void k_norm(const float* __restrict__ outS, const float* __restrict__ dinv2,
                       const int* __restrict__ i_idx, const int* __restrict__ j_idx,
                       float* __restrict__ out) {
    int t = blockIdx.x * 256 + threadIdx.x;   // 2*NE threads
    int r, c;
    if (t < NE) { r = i_idx[t]; c = j_idx[t]; }
    else        { r = j_idx[t - NE]; c = i_idx[t - NE]; }
    out[t] = dinv2[r] * outS[t] * dinv2[c];
}

extern "C" void kernel_launch(void* const* d_in, const int* in_sizes, int n_in,
                              void* d_out, int out_size, void* d_ws, size_t ws_size,
                              hipStream_t stream) {
    const float* features = (const float*)d_in[0];
    const float* W1       = (const float*)d_in[1];
    const float* b1       = (const float*)d_in[2];
    const float* W2       = (const float*)d_in[3];
    const float* b2       = (const float*)d_in[4];
    const float* s_d      = (const float*)d_in[5];
    const int*   adj_row  = (const int*)d_in[6];
    const int*   adj_col  = (const int*)d_in[7];
    const int*   i_idx    = (const int*)d_in[8];
    const int*   j_idx    = (const int*)d_in[9];
    float* out = (float*)d_out;

    // Workspace layout (element offsets in floats/ints):
    // [B (N*64)][C (N*64)][deg2 (N)][degcnt int (N)]  <- zero region
    // [A (N*64)][dinv (N)][dinv2 (N)][sval (E)][hkeys (HSIZE)][hvals (HSIZE)]
    float* ws = (float*)d_ws;
    float* B      = ws;
    float* C      = B + N_NODES * 64;
    float* deg2   = C + N_NODES * 64;
    int*   degcnt = (int*)(deg2 + N_NODES);
    float* A      = (float*)(degcnt + N_NODES);
    float* dinv   = A + N_NODES * 64;
    float* dinv2  = dinv + N_NODES;
    float* sval   = dinv2 + N_NODES;
    int*   hkeys  = (int*)(sval + NE);
    int*   hvals  = hkeys + HSIZE;

    // Re-init (ws is poisoned 0xAA before every call)
    size_t zero_bytes = (size_t)(2 * N_NODES * 64 + 2 * N_NODES) * 4;
    hipMemsetAsync(B, 0, zero_bytes, stream);
    hipMemsetAsync(hkeys, 0xFF, (size_t)HSIZE * 4, stream);          // keys = -1
    hipMemsetAsync(hvals, 0x7F, (size_t)HSIZE * 4, stream);          // vals = big

    // GCN degree / dinv
    k_degcount<<<(NE + 255) / 256, 256, 0, stream>>>(adj_col, degcnt);
    k_dinv<<<(N_NODES + 255) / 256, 256, 0, stream>>>(degcnt, dinv);

    // Layer 1: A = X@W1 ; B = relu(agg(A) + dinv^2*A + b1)
    k_gemm<<<N_NODES / 32, 256, 0, stream>>>(features, W1, A);
    k_agg<<<NE * 64 / 256, 256, 0, stream>>>(A, B, adj_row, adj_col, dinv);
    k_fin1<<<N_NODES * 64 / 256, 256, 0, stream>>>(B, A, dinv, b1);

    // Layer 2: A = B@W2 ; C = normalize(agg(A) + dinv^2*A + b2)
    k_gemm<<<N_NODES / 32, 256, 0, stream>>>(B, W2, A);
    k_agg<<<NE * 64 / 256, 256, 0, stream>>>(A, C, adj_row, adj_col, dinv);
    k_fin2norm<<<N_NODES * 64 / 256, 256, 0, stream>>>(C, A, dinv, b2);

    // Edge scores + hash build
    k_edge<<<NE * 16 / 256, 256, 0, stream>>>(C, s_d, i_idx, j_idx, sval, hkeys, hvals);

    // Symmetrize (writes vals_s = out[2E..4E), accumulates deg2)
    float* outS = out + 2 * NE;
    k_sym<<<NE / 256, 256, 0, stream>>>(sval, i_idx, j_idx, hkeys, hvals, outS, deg2);
    k_dinv2<<<(N_NODES + 255) / 256, 256, 0, stream>>>(deg2, dinv2);

    // Final: vals_norm = out[0..2E)
    k_norm<<<2 * NE / 256, 256, 0, stream>>>(outS, dinv2, i_idx, j_idx, out);
}

// Round 2
// 523.165 us; speedup vs baseline: 1.6398x; 1.6398x over previous
//
#include <hip/hip_runtime.h>

// Problem constants (match reference)
#define N_NODES 40000
#define ISIZE   64
#define KNN     24
#define NE      (N_NODES * KNN)      // 960000 edges (= E_ADJ as well)
#define OMEGA   0.9f
#define CAP     64                   // per-node bucket capacity (max deg ~46)
#define HSIZE_LOG 21
#define HSIZE   (1u << HSIZE_LOG)    // 2097152 slots
#define HMASK   (HSIZE - 1u)

__device__ __forceinline__ unsigned hash_key(int key) {
    unsigned x = (unsigned)key;
    x *= 2654435761u;
    x ^= x >> 15;
    return x & HMASK;
}

// ---- bucket edges by destination col; cnt[] ends up as the degree --------
__global__ void k_scatter(const int* __restrict__ row, const int* __restrict__ col,
                          int* __restrict__ cnt, int* __restrict__ ebuf,
                          int* __restrict__ ovf, int* __restrict__ ovf_cnt) {
    int e = blockIdx.x * 256 + threadIdx.x;
    if (e >= NE) return;
    int c = col[e];
    int slot = atomicAdd(&cnt[c], 1);
    if (slot < CAP) ebuf[c * CAP + slot] = row[e];
    else { int p = atomicAdd(ovf_cnt, 1); ovf[p] = e; }
}

__global__ void k_dinv(const int* __restrict__ cnt, float* __restrict__ dinv) {
    int n = blockIdx.x * 256 + threadIdx.x;
    if (n < N_NODES) dinv[n] = rsqrtf(1.0f + (float)cnt[n]);
}

// ---- overflow fallback (normally 0 edges): out[c] += dinv[r]*xw[r] -------
__global__ void k_ovf(const float* __restrict__ xw, float* __restrict__ out,
                      const float* __restrict__ dinv,
                      const int* __restrict__ ovf, const int* __restrict__ ovf_cnt,
                      const int* __restrict__ row, const int* __restrict__ col) {
    int total = ovf_cnt[0] * 64;
    for (int t = blockIdx.x * 256 + threadIdx.x; t < total; t += gridDim.x * 256) {
        int e = ovf[t >> 6];
        int f = t & 63;
        int r = row[e], c = col[e];
        atomicAdd(&out[c * 64 + f], dinv[r] * xw[r * 64 + f]);
    }
}

// ---- Y = X @ W  (N x 64) * (64 x 64) -------------------------------------
__global__ void k_gemm(const float* __restrict__ X, const float* __restrict__ W,
                       float* __restrict__ Y) {
    __shared__ float sW[64 * 64];
    __shared__ float sX[32 * 64];
    int row0 = blockIdx.x * 32;
    for (int t = threadIdx.x; t < 64 * 64; t += 256) sW[t] = W[t];
    for (int t = threadIdx.x; t < 32 * 64; t += 256) sX[t] = X[row0 * 64 + t];
    __syncthreads();
    int col = threadIdx.x & 63;
    int rl  = threadIdx.x >> 6;           // 0..3
    for (int r = rl; r < 32; r += 4) {
        float acc = 0.0f;
#pragma unroll
        for (int kk = 0; kk < 64; kk++) acc += sX[r * 64 + kk] * sW[kk * 64 + col];
        Y[(row0 + r) * 64 + col] = acc;
    }
}

// ---- pull aggregation, one wave per node, fused epilogue -----------------
// out[n] = epi( dinv[n] * (ovf_base + sum_e dinv[r_e]*xw[r_e]) + dinv[n]^2*xw[n] + bias )
template<bool RELU, bool NORM>
__global__ void k_aggf(const float* __restrict__ xw, float* __restrict__ out,
                       const float* __restrict__ dinv, const int* __restrict__ cnt,
                       const int* __restrict__ ebuf, const float* __restrict__ bias) {
    int wave = (blockIdx.x * 256 + threadIdx.x) >> 6;   // node id
    int lane = threadIdx.x & 63;
    if (wave >= N_NODES) return;
    int n = wave;
    int deg = cnt[n];
    int bucketed = min(deg, CAP);

    // lane d holds bucket entry d: row index + its dinv (coalesced loads)
    int   r_l  = 0;
    float di_l = 0.0f;
    if (lane < bucketed) {
        r_l  = ebuf[n * CAP + lane];
        di_l = dinv[r_l];
    }

    float acc = out[n * 64 + lane];   // overflow contributions (zero normally)
    int d = 0;
    for (; d + 3 < bucketed; d += 4) {
        int   r0 = __shfl(r_l, d),     r1 = __shfl(r_l, d + 1);
        int   r2 = __shfl(r_l, d + 2), r3 = __shfl(r_l, d + 3);
        float c0 = __shfl(di_l, d),     c1 = __shfl(di_l, d + 1);
        float c2 = __shfl(di_l, d + 2), c3 = __shfl(di_l, d + 3);
        float x0 = xw[r0 * 64 + lane];
        float x1 = xw[r1 * 64 + lane];
        float x2 = xw[r2 * 64 + lane];
        float x3 = xw[r3 * 64 + lane];
        acc += c0 * x0 + c1 * x1 + c2 * x2 + c3 * x3;
    }
    for (; d < bucketed; d++) {
        int   r = __shfl(r_l, d);
        float c = __shfl(di_l, d);
        acc += c * xw[r * 64 + lane];
    }

    float di  = dinv[n];
    float val = di * acc + di * di * xw[n * 64 + lane] + bias[lane];
    if (RELU) val = fmaxf(val, 0.0f);
    if (NORM) {
        float v2 = val * val;
#pragma unroll
        for (int m = 1; m < 64; m <<= 1) v2 += __shfl_xor(v2, m);
        val = val / fmaxf(sqrtf(v2), 1e-12f);
    }
    out[n * 64 + lane] = val;
}

// ---- per-edge score + hash insert ----------------------------------------
__global__ void k_edge(const float* __restrict__ h, const float* __restrict__ s_d,
                       const int* __restrict__ i_idx, const int* __restrict__ j_idx,
                       float* __restrict__ sval,
                       int* __restrict__ hkeys, int* __restrict__ hvals) {
    int t = blockIdx.x * 256 + threadIdx.x;   // NE*16 threads
    int e = t >> 4;
    int q = t & 15;
    int i = i_idx[e], j = j_idx[e];
    const float4* h4 = (const float4*)h;
    float4 a = h4[i * 16 + q];
    float4 b = h4[j * 16 + q];
    float s = a.x * b.x + a.y * b.y + a.z * b.z + a.w * b.w;
#pragma unroll
    for (int m = 1; m < 16; m <<= 1) s += __shfl_xor(s, m);
    if (q == 0) {
        float v = OMEGA * fmaxf(s, 0.0f) + (1.0f - OMEGA) * s_d[e];
        sval[e] = v;
        int key = i * N_NODES + j;            // fits int32
        unsigned slot = hash_key(key);
        while (true) {
            int old = atomicCAS(&hkeys[slot], -1, key);
            if (old == -1 || old == key) { atomicMin(&hvals[slot], e); break; }
            slot = (slot + 1u) & HMASK;
        }
    }
}

// ---- symmetrize: lookup reverse edge, write vals_s, accumulate degree ----
__global__ void k_sym(const float* __restrict__ sval,
                      const int* __restrict__ i_idx, const int* __restrict__ j_idx,
                      const int* __restrict__ hkeys, const int* __restrict__ hvals,
                      float* __restrict__ outS,     // d_out + 2E, holds vals_s [2E]
                      float* __restrict__ deg2) {
    int e = blockIdx.x * 256 + threadIdx.x;   // NE threads
    int i = i_idx[e], j = j_idx[e];
    int rkey = j * N_NODES + i;
    unsigned slot = hash_key(rkey);
    int rev = -1;
    while (true) {
        int k = hkeys[slot];
        if (k == -1) break;
        if (k == rkey) { rev = hvals[slot]; break; }
        slot = (slot + 1u) & HMASK;
    }
    float v = sval[e];
    bool found = (rev >= 0);
    if (found) v = 0.5f * (v + sval[rev]);
    float v2 = found ? 0.0f : v;
    outS[e] = v;
    outS[NE + e] = v2;
    atomicAdd(&deg2[i], v);
    atomicAdd(&deg2[j], v2);
}

__global__ void k_dinv2(const float* __restrict__ deg2, float* __restrict__ dinv2) {
    int n = blockIdx.x * 256 + threadIdx.x;
    if (n < N_NODES) {
        float d = deg2[n];
        dinv2[n] = (d > 0.0f) ? rsqrtf(fmaxf(d, 1e-12f)) : 0.0f;
    }
}

// ---- final normalization: vals_norm = dinv2[r] * vals_s * dinv2[c] -------
__global__ void k_norm(const float* __restrict__ outS, const float* __restrict__ dinv2,
                       const int* __restrict__ i_idx, const int* __restrict__ j_idx,
                       float* __restrict__ out) {
    int t = blockIdx.x * 256 + threadIdx.x;   // 2*NE threads
    int r, c;
    if (t < NE) { r = i_idx[t]; c = j_idx[t]; }
    else        { r = j_idx[t - NE]; c = i_idx[t - NE]; }
    out[t] = dinv2[r] * outS[t] * dinv2[c];
}

extern "C" void kernel_launch(void* const* d_in, const int* in_sizes, int n_in,
                              void* d_out, int out_size, void* d_ws, size_t ws_size,
                              hipStream_t stream) {
    const float* features = (const float*)d_in[0];
    const float* W1       = (const float*)d_in[1];
    const float* b1       = (const float*)d_in[2];
    const float* W2       = (const float*)d_in[3];
    const float* b2       = (const float*)d_in[4];
    const float* s_d      = (const float*)d_in[5];
    const int*   adj_row  = (const int*)d_in[6];
    const int*   adj_col  = (const int*)d_in[7];
    const int*   i_idx    = (const int*)d_in[8];
    const int*   j_idx    = (const int*)d_in[9];
    float* out = (float*)d_out;

    const int N64 = N_NODES * 64;
    // Workspace layout:
    // zero region: [B N64][C N64][deg2 N][cnt N int][ovf_cnt 16 int]
    // then:        [A N64][dinv N][dinv2 N][sval NE][ebuf N*CAP int][ovf NE int]
    //              [hkeys HSIZE int][hvals HSIZE int]
    float* ws = (float*)d_ws;
    float* B       = ws;
    float* C       = B + N64;
    float* deg2    = C + N64;
    int*   cnt     = (int*)(deg2 + N_NODES);
    int*   ovf_cnt = cnt + N_NODES;
    float* A       = (float*)(ovf_cnt + 16);
    float* dinv    = A + N64;
    float* dinv2   = dinv + N_NODES;
    float* sval    = dinv2 + N_NODES;
    int*   ebuf    = (int*)(sval + NE);
    int*   ovf     = ebuf + N_NODES * CAP;
    int*   hkeys   = ovf + NE;
    int*   hvals   = hkeys + HSIZE;

    // Re-init (ws is poisoned 0xAA before every call)
    size_t zero_bytes = (size_t)(2 * N64 + 2 * N_NODES + 16) * 4;
    hipMemsetAsync(B, 0, zero_bytes, stream);
    hipMemsetAsync(hkeys, 0xFF, (size_t)HSIZE * 4, stream);   // keys = -1
    hipMemsetAsync(hvals, 0x7F, (size_t)HSIZE * 4, stream);   // vals = big

    // Bucket adjacency by destination (also produces degree counts)
    k_scatter<<<(NE + 255) / 256, 256, 0, stream>>>(adj_row, adj_col, cnt, ebuf, ovf, ovf_cnt);
    k_dinv<<<(N_NODES + 255) / 256, 256, 0, stream>>>(cnt, dinv);

    // Layer 1: A = X@W1 ; B = relu(agg(A) + dinv^2*A + b1)
    k_gemm<<<N_NODES / 32, 256, 0, stream>>>(features, W1, A);
    k_ovf<<<16, 256, 0, stream>>>(A, B, dinv, ovf, ovf_cnt, adj_row, adj_col);
    k_aggf<true, false><<<(N_NODES * 64) / 256, 256, 0, stream>>>(A, B, dinv, cnt, ebuf, b1);

    // Layer 2: A = B@W2 ; C = normalize(agg(A) + dinv^2*A + b2)
    k_gemm<<<N_NODES / 32, 256, 0, stream>>>(B, W2, A);
    k_ovf<<<16, 256, 0, stream>>>(A, C, dinv, ovf, ovf_cnt, adj_row, adj_col);
    k_aggf<false, true><<<(N_NODES * 64) / 256, 256, 0, stream>>>(A, C, dinv, cnt, ebuf, b2);

    // Edge scores + hash build
    k_edge<<<NE * 16 / 256, 256, 0, stream>>>(C, s_d, i_idx, j_idx, sval, hkeys, hvals);

    // Symmetrize (writes vals_s = out[2E..4E), accumulates deg2)
    float* outS = out + 2 * NE;
    k_sym<<<NE / 256, 256, 0, stream>>>(sval, i_idx, j_idx, hkeys, hvals, outS, deg2);
    k_dinv2<<<(N_NODES + 255) / 256, 256, 0, stream>>>(deg2, dinv2);

    // Final: vals_norm = out[0..2E)
    k_norm<<<2 * NE / 256, 256, 0, stream>>>(outS, dinv2, i_idx, j_idx, out);
}

// Round 3
// 443.332 us; speedup vs baseline: 1.9350x; 1.1801x over previous
//
#include <hip/hip_runtime.h>

// Problem constants (match reference)
#define N_NODES 40000
#define ISIZE   64
#define KNN     24
#define NE      (N_NODES * KNN)      // 960000 edges (= E_ADJ as well)
#define OMEGA   0.9f
#define CAP     64                   // per-node bucket capacity (max deg ~46)

// ---- bucket edges by destination col; cnt[] ends up as the degree --------
__global__ void k_scatter(const int* __restrict__ row, const int* __restrict__ col,
                          int* __restrict__ cnt, int* __restrict__ ebuf,
                          int* __restrict__ ovf, int* __restrict__ ovf_cnt) {
    int e = blockIdx.x * 256 + threadIdx.x;
    if (e >= NE) return;
    int c = col[e];
    int slot = atomicAdd(&cnt[c], 1);
    if (slot < CAP) ebuf[c * CAP + slot] = row[e];
    else { int p = atomicAdd(ovf_cnt, 1); ovf[p] = e; }
}

__global__ void k_dinv(const int* __restrict__ cnt, float* __restrict__ dinv) {
    int n = blockIdx.x * 256 + threadIdx.x;
    if (n < N_NODES) dinv[n] = rsqrtf(1.0f + (float)cnt[n]);
}

// ---- overflow fallback (normally 0 edges): out[c] += dinv[r]*xw[r] -------
__global__ void k_ovf(const float* __restrict__ xw, float* __restrict__ out,
                      const float* __restrict__ dinv,
                      const int* __restrict__ ovf, const int* __restrict__ ovf_cnt,
                      const int* __restrict__ row, const int* __restrict__ col) {
    int total = ovf_cnt[0] * 64;
    for (int t = blockIdx.x * 256 + threadIdx.x; t < total; t += gridDim.x * 256) {
        int e = ovf[t >> 6];
        int f = t & 63;
        int r = row[e], c = col[e];
        atomicAdd(&out[c * 64 + f], dinv[r] * xw[r * 64 + f]);
    }
}

// ---- Y = X @ W  (N x 64) * (64 x 64) -------------------------------------
__global__ void k_gemm(const float* __restrict__ X, const float* __restrict__ W,
                       float* __restrict__ Y) {
    __shared__ float sW[64 * 64];
    __shared__ float sX[32 * 64];
    int row0 = blockIdx.x * 32;
    for (int t = threadIdx.x; t < 64 * 64; t += 256) sW[t] = W[t];
    for (int t = threadIdx.x; t < 32 * 64; t += 256) sX[t] = X[row0 * 64 + t];
    __syncthreads();
    int col = threadIdx.x & 63;
    int rl  = threadIdx.x >> 6;           // 0..3
    for (int r = rl; r < 32; r += 4) {
        float acc = 0.0f;
#pragma unroll
        for (int kk = 0; kk < 64; kk++) acc += sX[r * 64 + kk] * sW[kk * 64 + col];
        Y[(row0 + r) * 64 + col] = acc;
    }
}

// ---- pull aggregation, one wave per node, fused epilogue -----------------
// out[n] = epi( dinv[n] * (ovf_base + sum_e dinv[r_e]*xw[r_e]) + dinv[n]^2*xw[n] + bias )
template<bool RELU, bool NORM>
__global__ void k_aggf(const float* __restrict__ xw, float* __restrict__ out,
                       const float* __restrict__ dinv, const int* __restrict__ cnt,
                       const int* __restrict__ ebuf, const float* __restrict__ bias) {
    int wave = (blockIdx.x * 256 + threadIdx.x) >> 6;   // node id
    int lane = threadIdx.x & 63;
    if (wave >= N_NODES) return;
    int n = wave;
    int deg = cnt[n];
    int bucketed = min(deg, CAP);

    // lane d holds bucket entry d: row index + its dinv (coalesced loads)
    int   r_l  = 0;
    float di_l = 0.0f;
    if (lane < bucketed) {
        r_l  = ebuf[n * CAP + lane];
        di_l = dinv[r_l];
    }

    float acc = out[n * 64 + lane];   // overflow contributions (zero normally)
    int d = 0;
    for (; d + 3 < bucketed; d += 4) {
        int   r0 = __shfl(r_l, d),     r1 = __shfl(r_l, d + 1);
        int   r2 = __shfl(r_l, d + 2), r3 = __shfl(r_l, d + 3);
        float c0 = __shfl(di_l, d),     c1 = __shfl(di_l, d + 1);
        float c2 = __shfl(di_l, d + 2), c3 = __shfl(di_l, d + 3);
        float x0 = xw[r0 * 64 + lane];
        float x1 = xw[r1 * 64 + lane];
        float x2 = xw[r2 * 64 + lane];
        float x3 = xw[r3 * 64 + lane];
        acc += c0 * x0 + c1 * x1 + c2 * x2 + c3 * x3;
    }
    for (; d < bucketed; d++) {
        int   r = __shfl(r_l, d);
        float c = __shfl(di_l, d);
        acc += c * xw[r * 64 + lane];
    }

    float di  = dinv[n];
    float val = di * acc + di * di * xw[n * 64 + lane] + bias[lane];
    if (RELU) val = fmaxf(val, 0.0f);
    if (NORM) {
        float v2 = val * val;
#pragma unroll
        for (int m = 1; m < 64; m <<= 1) v2 += __shfl_xor(v2, m);
        val = val / fmaxf(sqrtf(v2), 1e-12f);
    }
    out[n * 64 + lane] = val;
}

// ---- fused edge score + reverse-edge match + symmetrize + degree ---------
// i_idx == repeat(arange(N), K): edge e has i = e/K, and the reverse edge of
// (i,j) can only be among node j's K contiguous edges [j*K, j*K+K).
// relu(dot) is symmetric, so v_sym = OMEGA*relu(dot) + 0.5*(1-OMEGA)*(s_d[e]+s_d[rev]).
__global__ void k_edgesym(const float* __restrict__ h, const float* __restrict__ s_d,
                          const int* __restrict__ j_idx,
                          float* __restrict__ outS,     // d_out + 2E, holds vals_s [2E]
                          float* __restrict__ deg2) {
    int t = blockIdx.x * 256 + threadIdx.x;   // NE*16 threads
    int e = t >> 4;
    int q = t & 15;
    int i = e / KNN;
    int j = j_idx[e];
    const float4* h4 = (const float4*)h;
    float4 a = h4[i * 16 + q];
    float4 b = h4[j * 16 + q];
    float s = a.x * b.x + a.y * b.y + a.z * b.z + a.w * b.w;

    // parallel scan of node j's edge slice for j_idx == i (min index wins)
    const int* jj = j_idx + j * KNN;
    int rt = 0x7fffffff;
    if (jj[q] == i) rt = q;
    if (q < KNN - 16) { if (jj[16 + q] == i) rt = min(rt, 16 + q); }

#pragma unroll
    for (int m = 1; m < 16; m <<= 1) {       // xor of bits<4 stays in the 16-lane group
        s  += __shfl_xor(s, m);
        rt  = min(rt, __shfl_xor(rt, m));
    }
    if (q == 0) {
        float base = OMEGA * fmaxf(s, 0.0f);
        float v, v2;
        if (rt != 0x7fffffff) {              // reverse edge exists
            int rev = j * KNN + rt;
            v  = base + 0.5f * (1.0f - OMEGA) * (s_d[e] + s_d[rev]);
            v2 = 0.0f;
        } else {
            v  = base + (1.0f - OMEGA) * s_d[e];
            v2 = v;
        }
        outS[e] = v;
        outS[NE + e] = v2;
        atomicAdd(&deg2[i], v);
        if (v2 != 0.0f) atomicAdd(&deg2[j], v2);
    }
}

__global__ void k_dinv2(const float* __restrict__ deg2, float* __restrict__ dinv2) {
    int n = blockIdx.x * 256 + threadIdx.x;
    if (n < N_NODES) {
        float d = deg2[n];
        dinv2[n] = (d > 0.0f) ? rsqrtf(fmaxf(d, 1e-12f)) : 0.0f;
    }
}

// ---- final normalization: vals_norm = dinv2[r] * vals_s * dinv2[c] -------
__global__ void k_norm(const float* __restrict__ outS, const float* __restrict__ dinv2,
                       const int* __restrict__ j_idx, float* __restrict__ out) {
    int t = blockIdx.x * 256 + threadIdx.x;   // 2*NE threads
    int r, c;
    if (t < NE) { r = t / KNN; c = j_idx[t]; }
    else        { int e = t - NE; r = j_idx[e]; c = e / KNN; }
    out[t] = dinv2[r] * outS[t] * dinv2[c];
}

extern "C" void kernel_launch(void* const* d_in, const int* in_sizes, int n_in,
                              void* d_out, int out_size, void* d_ws, size_t ws_size,
                              hipStream_t stream) {
    const float* features = (const float*)d_in[0];
    const float* W1       = (const float*)d_in[1];
    const float* b1       = (const float*)d_in[2];
    const float* W2       = (const float*)d_in[3];
    const float* b2       = (const float*)d_in[4];
    const float* s_d      = (const float*)d_in[5];
    const int*   adj_row  = (const int*)d_in[6];
    const int*   adj_col  = (const int*)d_in[7];
    const int*   j_idx    = (const int*)d_in[9];
    float* out = (float*)d_out;

    const int N64 = N_NODES * 64;
    // Workspace layout:
    // zero region: [B N64][C N64][deg2 N][cnt N int][ovf_cnt 16 int]
    // then:        [A N64][dinv N][dinv2 N][ebuf N*CAP int][ovf NE int]
    float* ws = (float*)d_ws;
    float* B       = ws;
    float* C       = B + N64;
    float* deg2    = C + N64;
    int*   cnt     = (int*)(deg2 + N_NODES);
    int*   ovf_cnt = cnt + N_NODES;
    float* A       = (float*)(ovf_cnt + 16);
    float* dinv    = A + N64;
    float* dinv2   = dinv + N_NODES;
    int*   ebuf    = (int*)(dinv2 + N_NODES);
    int*   ovf     = ebuf + N_NODES * CAP;

    // Re-init (ws is poisoned 0xAA before every call)
    size_t zero_bytes = (size_t)(2 * N64 + 2 * N_NODES + 16) * 4;
    hipMemsetAsync(B, 0, zero_bytes, stream);

    // Bucket adjacency by destination (also produces degree counts)
    k_scatter<<<(NE + 255) / 256, 256, 0, stream>>>(adj_row, adj_col, cnt, ebuf, ovf, ovf_cnt);
    k_dinv<<<(N_NODES + 255) / 256, 256, 0, stream>>>(cnt, dinv);

    // Layer 1: A = X@W1 ; B = relu(agg(A) + dinv^2*A + b1)
    k_gemm<<<N_NODES / 32, 256, 0, stream>>>(features, W1, A);
    k_ovf<<<16, 256, 0, stream>>>(A, B, dinv, ovf, ovf_cnt, adj_row, adj_col);
    k_aggf<true, false><<<(N_NODES * 64) / 256, 256, 0, stream>>>(A, B, dinv, cnt, ebuf, b1);

    // Layer 2: A = B@W2 ; C = normalize(agg(A) + dinv^2*A + b2)
    k_gemm<<<N_NODES / 32, 256, 0, stream>>>(B, W2, A);
    k_ovf<<<16, 256, 0, stream>>>(A, C, dinv, ovf, ovf_cnt, adj_row, adj_col);
    k_aggf<false, true><<<(N_NODES * 64) / 256, 256, 0, stream>>>(A, C, dinv, cnt, ebuf, b2);

    // Fused edge score + symmetrize (writes vals_s = out[2E..4E), accumulates deg2)
    float* outS = out + 2 * NE;
    k_edgesym<<<NE * 16 / 256, 256, 0, stream>>>(C, s_d, j_idx, outS, deg2);
    k_dinv2<<<(N_NODES + 255) / 256, 256, 0, stream>>>(deg2, dinv2);

    // Final: vals_norm = out[0..2E)
    k_norm<<<2 * NE / 256, 256, 0, stream>>>(outS, dinv2, j_idx, out);
}

// Round 4
// 434.040 us; speedup vs baseline: 1.9765x; 1.0214x over previous
//
#include <hip/hip_runtime.h>

// Problem constants (match reference)
#define N_NODES 40000
#define ISIZE   64
#define KNN     24
#define NE      (N_NODES * KNN)      // 960000 edges (= E_ADJ as well)
#define OMEGA   0.9f
#define CAP     64                   // per-node bucket capacity (max deg ~46)

// ---- bf16 helpers (storage-only precision; all math in fp32) -------------
__device__ __forceinline__ float bf2f(unsigned short s) {
    return __uint_as_float(((unsigned)s) << 16);
}
__device__ __forceinline__ unsigned short f2bf(float f) {  // round-nearest-even
    unsigned u = __float_as_uint(f);
    u += 0x7fffu + ((u >> 16) & 1u);
    return (unsigned short)(u >> 16);
}
__device__ __forceinline__ float bflo(unsigned u) { return __uint_as_float(u << 16); }
__device__ __forceinline__ float bfhi(unsigned u) { return __uint_as_float(u & 0xffff0000u); }
__device__ __forceinline__ float ldf(float x) { return x; }
__device__ __forceinline__ float ldf(unsigned short x) { return bf2f(x); }

// ---- bucket edges by destination col; cnt[] ends up as the degree --------
__global__ void k_scatter(const int* __restrict__ row, const int* __restrict__ col,
                          int* __restrict__ cnt, int* __restrict__ ebuf,
                          int* __restrict__ ovf, int* __restrict__ ovf_cnt) {
    int e = blockIdx.x * 256 + threadIdx.x;
    if (e >= NE) return;
    int c = col[e];
    int slot = atomicAdd(&cnt[c], 1);
    if (slot < CAP) ebuf[c * CAP + slot] = row[e];
    else { int p = atomicAdd(ovf_cnt, 1); ovf[p] = e; }
}

__global__ void k_dinv(const int* __restrict__ cnt, float* __restrict__ dinv) {
    int n = blockIdx.x * 256 + threadIdx.x;
    if (n < N_NODES) dinv[n] = rsqrtf(1.0f + (float)cnt[n]);
}

// ---- overflow fallback (normally 0 edges): ovfacc[c] += dinv[r]*xw[r] ----
__global__ void k_ovf(const unsigned short* __restrict__ xw, float* __restrict__ ovfacc,
                      const float* __restrict__ dinv,
                      const int* __restrict__ ovf, const int* __restrict__ ovf_cnt,
                      const int* __restrict__ row, const int* __restrict__ col) {
    int total = ovf_cnt[0] * 64;
    for (int t = blockIdx.x * 256 + threadIdx.x; t < total; t += gridDim.x * 256) {
        int e = ovf[t >> 6];
        int f = t & 63;
        int r = row[e], c = col[e];
        atomicAdd(&ovfacc[c * 64 + f], dinv[r] * bf2f(xw[r * 64 + f]));
    }
}

// ---- Y = X @ W  (N x 64) * (64 x 64), bf16 output ------------------------
template<typename T>
__global__ void k_gemm(const T* __restrict__ X, const float* __restrict__ W,
                       unsigned short* __restrict__ Y) {
    __shared__ float sW[64 * 64];
    __shared__ float sX[32 * 64];
    int row0 = blockIdx.x * 32;
    for (int t = threadIdx.x; t < 64 * 64; t += 256) sW[t] = W[t];
    for (int t = threadIdx.x; t < 32 * 64; t += 256) sX[t] = ldf(X[row0 * 64 + t]);
    __syncthreads();
    int col = threadIdx.x & 63;
    int rl  = threadIdx.x >> 6;           // 0..3
    for (int r = rl; r < 32; r += 4) {
        float acc = 0.0f;
#pragma unroll
        for (int kk = 0; kk < 64; kk++) acc += sX[r * 64 + kk] * sW[kk * 64 + col];
        Y[(row0 + r) * 64 + col] = f2bf(acc);
    }
}

// ---- pull aggregation, one wave per node, fused epilogue (bf16 in/out) ---
template<bool RELU, bool NORM>
__global__ void k_aggf(const unsigned short* __restrict__ xw, unsigned short* __restrict__ out,
                       const float* __restrict__ ovfacc,
                       const float* __restrict__ dinv, const int* __restrict__ cnt,
                       const int* __restrict__ ebuf, const float* __restrict__ bias) {
    int wave = (blockIdx.x * 256 + threadIdx.x) >> 6;   // node id
    int lane = threadIdx.x & 63;
    if (wave >= N_NODES) return;
    int n = wave;
    int deg = cnt[n];
    int bucketed = min(deg, CAP);

    // lane d holds bucket entry d: row index + its dinv (coalesced loads)
    int   r_l  = 0;
    float di_l = 0.0f;
    if (lane < bucketed) {
        r_l  = ebuf[n * CAP + lane];
        di_l = dinv[r_l];
    }

    float acc = ovfacc[n * 64 + lane];   // overflow contributions (zero normally)
    int d = 0;
    for (; d + 3 < bucketed; d += 4) {
        int   r0 = __shfl(r_l, d),     r1 = __shfl(r_l, d + 1);
        int   r2 = __shfl(r_l, d + 2), r3 = __shfl(r_l, d + 3);
        float c0 = __shfl(di_l, d),     c1 = __shfl(di_l, d + 1);
        float c2 = __shfl(di_l, d + 2), c3 = __shfl(di_l, d + 3);
        float x0 = bf2f(xw[r0 * 64 + lane]);
        float x1 = bf2f(xw[r1 * 64 + lane]);
        float x2 = bf2f(xw[r2 * 64 + lane]);
        float x3 = bf2f(xw[r3 * 64 + lane]);
        acc += c0 * x0 + c1 * x1 + c2 * x2 + c3 * x3;
    }
    for (; d < bucketed; d++) {
        int   r = __shfl(r_l, d);
        float c = __shfl(di_l, d);
        acc += c * bf2f(xw[r * 64 + lane]);
    }

    float di  = dinv[n];
    float val = di * acc + di * di * bf2f(xw[n * 64 + lane]) + bias[lane];
    if (RELU) val = fmaxf(val, 0.0f);
    if (NORM) {
        float v2 = val * val;
#pragma unroll
        for (int m = 1; m < 64; m <<= 1) v2 += __shfl_xor(v2, m);
        val = val / fmaxf(sqrtf(v2), 1e-12f);
    }
    out[n * 64 + lane] = f2bf(val);
}

// ---- fused edge score + reverse-edge match + symmetrize + degree ---------
// h is bf16: one row = 64 bf16 = 128 B = 16 uint2; 16 lanes per edge.
__global__ void k_edgesym(const uint2* __restrict__ hb, const float* __restrict__ s_d,
                          const int* __restrict__ j_idx,
                          float* __restrict__ outS,     // d_out + 2E, holds vals_s [2E]
                          float* __restrict__ deg2) {
    int t = blockIdx.x * 256 + threadIdx.x;   // NE*16 threads
    int e = t >> 4;
    int q = t & 15;
    int i = e / KNN;
    int j = j_idx[e];
    uint2 a = hb[i * 16 + q];
    uint2 b = hb[j * 16 + q];
    float s = bflo(a.x) * bflo(b.x) + bfhi(a.x) * bfhi(b.x)
            + bflo(a.y) * bflo(b.y) + bfhi(a.y) * bfhi(b.y);

    // parallel scan of node j's edge slice for j_idx == i (min index wins)
    const int* jj = j_idx + j * KNN;
    int rt = 0x7fffffff;
    if (jj[q] == i) rt = q;
    if (q < KNN - 16) { if (jj[16 + q] == i) rt = min(rt, 16 + q); }

#pragma unroll
    for (int m = 1; m < 16; m <<= 1) {       // xor of bits<4 stays in the 16-lane group
        s  += __shfl_xor(s, m);
        rt  = min(rt, __shfl_xor(rt, m));
    }
    if (q == 0) {
        float base = OMEGA * fmaxf(s, 0.0f);
        float v, v2;
        if (rt != 0x7fffffff) {              // reverse edge exists
            int rev = j * KNN + rt;
            v  = base + 0.5f * (1.0f - OMEGA) * (s_d[e] + s_d[rev]);
            v2 = 0.0f;
        } else {
            v  = base + (1.0f - OMEGA) * s_d[e];
            v2 = v;
        }
        outS[e] = v;
        outS[NE + e] = v2;
        atomicAdd(&deg2[i], v);
        if (v2 != 0.0f) atomicAdd(&deg2[j], v2);
    }
}

__global__ void k_dinv2(const float* __restrict__ deg2, float* __restrict__ dinv2) {
    int n = blockIdx.x * 256 + threadIdx.x;
    if (n < N_NODES) {
        float d = deg2[n];
        dinv2[n] = (d > 0.0f) ? rsqrtf(fmaxf(d, 1e-12f)) : 0.0f;
    }
}

// ---- final normalization: vals_norm = dinv2[r] * vals_s * dinv2[c] -------
__global__ void k_norm(const float* __restrict__ outS, const float* __restrict__ dinv2,
                       const int* __restrict__ j_idx, float* __restrict__ out) {
    int t = blockIdx.x * 256 + threadIdx.x;   // 2*NE threads
    int r, c;
    if (t < NE) { r = t / KNN; c = j_idx[t]; }
    else        { int e = t - NE; r = j_idx[e]; c = e / KNN; }
    out[t] = dinv2[r] * outS[t] * dinv2[c];
}

extern "C" void kernel_launch(void* const* d_in, const int* in_sizes, int n_in,
                              void* d_out, int out_size, void* d_ws, size_t ws_size,
                              hipStream_t stream) {
    const float* features = (const float*)d_in[0];
    const float* W1       = (const float*)d_in[1];
    const float* b1       = (const float*)d_in[2];
    const float* W2       = (const float*)d_in[3];
    const float* b2       = (const float*)d_in[4];
    const float* s_d      = (const float*)d_in[5];
    const int*   adj_row  = (const int*)d_in[6];
    const int*   adj_col  = (const int*)d_in[7];
    const int*   j_idx    = (const int*)d_in[9];
    float* out = (float*)d_out;

    const int N64 = N_NODES * 64;
    // Workspace layout (floats unless noted):
    // zero region: [OVFACC N64][deg2 N][cnt N int][ovf_cnt 16 int]
    // then:        [dinv N][dinv2 N][A16 N64 ushort][B16 N64 ushort][H16 N64 ushort]
    //              [ebuf N*CAP int][ovf NE int]
    float* ws = (float*)d_ws;
    float* OVFACC  = ws;
    float* deg2    = OVFACC + N64;
    int*   cnt     = (int*)(deg2 + N_NODES);
    int*   ovf_cnt = cnt + N_NODES;
    float* dinv    = (float*)(ovf_cnt + 16);
    float* dinv2   = dinv + N_NODES;
    unsigned short* A16 = (unsigned short*)(dinv2 + N_NODES);
    unsigned short* B16 = A16 + N64;
    unsigned short* H16 = B16 + N64;
    int*   ebuf    = (int*)(H16 + N64);
    int*   ovf     = ebuf + N_NODES * CAP;

    // Re-init (ws is poisoned 0xAA before every call)
    size_t zero_bytes = (size_t)(N64 + N_NODES + N_NODES + 16) * 4;
    hipMemsetAsync(OVFACC, 0, zero_bytes, stream);

    // Bucket adjacency by destination (also produces degree counts)
    k_scatter<<<(NE + 255) / 256, 256, 0, stream>>>(adj_row, adj_col, cnt, ebuf, ovf, ovf_cnt);
    k_dinv<<<(N_NODES + 255) / 256, 256, 0, stream>>>(cnt, dinv);

    // Layer 1: A16 = X@W1 ; B16 = relu(agg(A16) + dinv^2*A16 + b1)
    k_gemm<float><<<N_NODES / 32, 256, 0, stream>>>(features, W1, A16);
    k_ovf<<<16, 256, 0, stream>>>(A16, OVFACC, dinv, ovf, ovf_cnt, adj_row, adj_col);
    k_aggf<true, false><<<(N_NODES * 64) / 256, 256, 0, stream>>>(A16, B16, OVFACC, dinv, cnt, ebuf, b1);

    // Re-zero overflow accumulator for layer 2 (stream-ordered after aggf1)
    hipMemsetAsync(OVFACC, 0, (size_t)N64 * 4, stream);

    // Layer 2: A16 = B16@W2 ; H16 = normalize(agg(A16) + dinv^2*A16 + b2)
    k_gemm<unsigned short><<<N_NODES / 32, 256, 0, stream>>>(B16, W2, A16);
    k_ovf<<<16, 256, 0, stream>>>(A16, OVFACC, dinv, ovf, ovf_cnt, adj_row, adj_col);
    k_aggf<false, true><<<(N_NODES * 64) / 256, 256, 0, stream>>>(A16, H16, OVFACC, dinv, cnt, ebuf, b2);

    // Fused edge score + symmetrize (writes vals_s = out[2E..4E), accumulates deg2)
    float* outS = out + 2 * NE;
    k_edgesym<<<NE * 16 / 256, 256, 0, stream>>>((const uint2*)H16, s_d, j_idx, outS, deg2);
    k_dinv2<<<(N_NODES + 255) / 256, 256, 0, stream>>>(deg2, dinv2);

    // Final: vals_norm = out[0..2E)
    k_norm<<<2 * NE / 256, 256, 0, stream>>>(outS, dinv2, j_idx, out);
}

// Round 5
// 325.202 us; speedup vs baseline: 2.6379x; 1.3347x over previous
//
#include <hip/hip_runtime.h>

// Problem constants (match reference)
#define N_NODES 40000
#define ISIZE   64
#define KNN     24
#define NE      (N_NODES * KNN)      // 960000 edges (= E_ADJ as well)
#define OMEGA   0.9f
#define CAP     64                   // per-node bucket capacity (max deg ~46)

// ---- bf16 helpers (storage-only precision; all math in fp32) -------------
__device__ __forceinline__ float bf2f(unsigned short s) {
    return __uint_as_float(((unsigned)s) << 16);
}
__device__ __forceinline__ unsigned short f2bf(float f) {  // round-nearest-even
    unsigned u = __float_as_uint(f);
    u += 0x7fffu + ((u >> 16) & 1u);
    return (unsigned short)(u >> 16);
}
__device__ __forceinline__ float bflo(unsigned u) { return __uint_as_float(u << 16); }
__device__ __forceinline__ float bfhi(unsigned u) { return __uint_as_float(u & 0xffff0000u); }
__device__ __forceinline__ float ldf(float x) { return x; }
__device__ __forceinline__ float ldf(unsigned short x) { return bf2f(x); }

// ---- bucket edges by destination col; cnt[] ends up as the degree --------
__global__ void k_scatter(const int* __restrict__ row, const int* __restrict__ col,
                          int* __restrict__ cnt, int* __restrict__ ebuf,
                          int* __restrict__ ovf, int* __restrict__ ovf_cnt) {
    int e = blockIdx.x * 256 + threadIdx.x;
    if (e >= NE) return;
    int c = col[e];
    int slot = atomicAdd(&cnt[c], 1);
    if (slot < CAP) ebuf[c * CAP + slot] = row[e];
    else { int p = atomicAdd(ovf_cnt, 1); ovf[p] = e; }
}

__global__ void k_dinv(const int* __restrict__ cnt, float* __restrict__ dinv) {
    int n = blockIdx.x * 256 + threadIdx.x;
    if (n < N_NODES) dinv[n] = rsqrtf(1.0f + (float)cnt[n]);
}

// ---- overflow fallback (normally 0 edges): ovfacc[c] += dinv[r]*xw[r] ----
__global__ void k_ovf(const unsigned short* __restrict__ xw, float* __restrict__ ovfacc,
                      const float* __restrict__ dinv,
                      const int* __restrict__ ovf, const int* __restrict__ ovf_cnt,
                      const int* __restrict__ row, const int* __restrict__ col) {
    int total = ovf_cnt[0] * 64;
    for (int t = blockIdx.x * 256 + threadIdx.x; t < total; t += gridDim.x * 256) {
        int e = ovf[t >> 6];
        int f = t & 63;
        int r = row[e], c = col[e];
        atomicAdd(&ovfacc[c * 64 + f], dinv[r] * bf2f(xw[r * 64 + f]));
    }
}

// ---- Y = X @ W  (N x 64) * (64 x 64), bf16 output ------------------------
template<typename T>
__global__ void k_gemm(const T* __restrict__ X, const float* __restrict__ W,
                       unsigned short* __restrict__ Y) {
    __shared__ float sW[64 * 64];
    __shared__ float sX[32 * 64];
    int row0 = blockIdx.x * 32;
    for (int t = threadIdx.x; t < 64 * 64; t += 256) sW[t] = W[t];
    for (int t = threadIdx.x; t < 32 * 64; t += 256) sX[t] = ldf(X[row0 * 64 + t]);
    __syncthreads();
    int col = threadIdx.x & 63;
    int rl  = threadIdx.x >> 6;           // 0..3
    for (int r = rl; r < 32; r += 4) {
        float acc = 0.0f;
#pragma unroll
        for (int kk = 0; kk < 64; kk++) acc += sX[r * 64 + kk] * sW[kk * 64 + col];
        Y[(row0 + r) * 64 + col] = f2bf(acc);
    }
}

// ---- pull aggregation, one wave per node, fused epilogue (bf16 in) -------
// NORM variant writes the row split into two half-feature arrays h0/h1.
template<bool RELU, bool NORM>
__global__ void k_aggf(const unsigned short* __restrict__ xw, unsigned short* __restrict__ out,
                       unsigned short* __restrict__ out_h1,   // only used when NORM
                       const float* __restrict__ ovfacc,
                       const float* __restrict__ dinv, const int* __restrict__ cnt,
                       const int* __restrict__ ebuf, const float* __restrict__ bias) {
    int wave = (blockIdx.x * 256 + threadIdx.x) >> 6;   // node id
    int lane = threadIdx.x & 63;
    if (wave >= N_NODES) return;
    int n = wave;
    int deg = cnt[n];
    int bucketed = min(deg, CAP);

    // lane d holds bucket entry d: row index + its dinv (coalesced loads)
    int   r_l  = 0;
    float di_l = 0.0f;
    if (lane < bucketed) {
        r_l  = ebuf[n * CAP + lane];
        di_l = dinv[r_l];
    }

    float acc = ovfacc[n * 64 + lane];   // overflow contributions (zero normally)
    int d = 0;
    for (; d + 3 < bucketed; d += 4) {
        int   r0 = __shfl(r_l, d),     r1 = __shfl(r_l, d + 1);
        int   r2 = __shfl(r_l, d + 2), r3 = __shfl(r_l, d + 3);
        float c0 = __shfl(di_l, d),     c1 = __shfl(di_l, d + 1);
        float c2 = __shfl(di_l, d + 2), c3 = __shfl(di_l, d + 3);
        float x0 = bf2f(xw[r0 * 64 + lane]);
        float x1 = bf2f(xw[r1 * 64 + lane]);
        float x2 = bf2f(xw[r2 * 64 + lane]);
        float x3 = bf2f(xw[r3 * 64 + lane]);
        acc += c0 * x0 + c1 * x1 + c2 * x2 + c3 * x3;
    }
    for (; d < bucketed; d++) {
        int   r = __shfl(r_l, d);
        float c = __shfl(di_l, d);
        acc += c * bf2f(xw[r * 64 + lane]);
    }

    float di  = dinv[n];
    float val = di * acc + di * di * bf2f(xw[n * 64 + lane]) + bias[lane];
    if (RELU) val = fmaxf(val, 0.0f);
    if (NORM) {
        float v2 = val * val;
#pragma unroll
        for (int m = 1; m < 64; m <<= 1) v2 += __shfl_xor(v2, m);
        val = val / fmaxf(sqrtf(v2), 1e-12f);
        // write feature-split halves: h0[n][lane] (lane<32) / h1[n][lane-32]
        unsigned short* dst = (lane < 32) ? out : out_h1;
        dst[n * 32 + (lane & 31)] = f2bf(val);
    } else {
        out[n * 64 + lane] = f2bf(val);
    }
}

// ---- pass A: partial dot over feature half 0 (h0 = 2.56 MB, L2-resident) -
// 8 lanes per edge; one uint2 (4 bf16) per lane.
__global__ void k_dot0(const uint2* __restrict__ h0b, const int* __restrict__ j_idx,
                       float* __restrict__ pdot) {
    int t = blockIdx.x * 256 + threadIdx.x;   // NE*8 threads
    int e = t >> 3;
    int q = t & 7;
    int i = e / KNN;
    int j = j_idx[e];
    uint2 a = h0b[i * 8 + q];
    uint2 b = h0b[j * 8 + q];
    float s = bflo(a.x) * bflo(b.x) + bfhi(a.x) * bfhi(b.x)
            + bflo(a.y) * bflo(b.y) + bfhi(a.y) * bfhi(b.y);
    s += __shfl_xor(s, 1);
    s += __shfl_xor(s, 2);
    s += __shfl_xor(s, 4);
    if (q == 0) pdot[e] = s;
}

// ---- pass B: half 1 dot + reverse-match scan + symmetrize ----------------
// deg2 out-edge part (contiguous) is NOT atomically accumulated here; only
// the random j-side (v2) atomic remains.
__global__ void k_edgesym2(const uint2* __restrict__ h1b, const float* __restrict__ pdot,
                           const float* __restrict__ s_d, const int* __restrict__ j_idx,
                           float* __restrict__ outS,     // d_out + 2E, holds vals_s [2E]
                           float* __restrict__ deg2in) {
    int t = blockIdx.x * 256 + threadIdx.x;   // NE*8 threads
    int e = t >> 3;
    int q = t & 7;
    int i = e / KNN;
    int j = j_idx[e];
    uint2 a = h1b[i * 8 + q];
    uint2 b = h1b[j * 8 + q];
    float s = bflo(a.x) * bflo(b.x) + bfhi(a.x) * bfhi(b.x)
            + bflo(a.y) * bflo(b.y) + bfhi(a.y) * bfhi(b.y);

    // scan node j's 24-edge slice for j_idx == i (min index wins); 8 lanes x 3
    const int* jj = j_idx + j * KNN;
    int rt = 0x7fffffff;
    if (jj[q] == i) rt = q;
    if (jj[8 + q] == i) rt = min(rt, 8 + q);
    if (jj[16 + q] == i) rt = min(rt, 16 + q);

#pragma unroll
    for (int m = 1; m < 8; m <<= 1) {
        s  += __shfl_xor(s, m);
        rt  = min(rt, __shfl_xor(rt, m));
    }
    if (q == 0) {
        s += pdot[e];
        float base = OMEGA * fmaxf(s, 0.0f);
        float v, v2;
        if (rt != 0x7fffffff) {              // reverse edge exists (rare)
            int rev = j * KNN + rt;
            v  = base + 0.5f * (1.0f - OMEGA) * (s_d[e] + s_d[rev]);
            v2 = 0.0f;
        } else {
            v  = base + (1.0f - OMEGA) * s_d[e];
            v2 = v;
        }
        outS[e] = v;
        outS[NE + e] = v2;
        if (v2 != 0.0f) atomicAdd(&deg2in[j], v2);
    }
}

// ---- dinv2: atomic-free out-edge segment sum + random in-edge part -------
__global__ void k_dinv2(const float* __restrict__ outS, const float* __restrict__ deg2in,
                        float* __restrict__ dinv2) {
    int n = blockIdx.x * 256 + threadIdx.x;
    if (n >= N_NODES) return;
    float d = deg2in[n];
    const float* p = outS + n * KNN;
#pragma unroll
    for (int q = 0; q < KNN; q++) d += p[q];
    dinv2[n] = (d > 0.0f) ? rsqrtf(fmaxf(d, 1e-12f)) : 0.0f;
}

// ---- final normalization: vals_norm = dinv2[r] * vals_s * dinv2[c] -------
__global__ void k_norm(const float* __restrict__ outS, const float* __restrict__ dinv2,
                       const int* __restrict__ j_idx, float* __restrict__ out) {
    int t = blockIdx.x * 256 + threadIdx.x;   // 2*NE threads
    int r, c;
    if (t < NE) { r = t / KNN; c = j_idx[t]; }
    else        { int e = t - NE; r = j_idx[e]; c = e / KNN; }
    out[t] = dinv2[r] * outS[t] * dinv2[c];
}

extern "C" void kernel_launch(void* const* d_in, const int* in_sizes, int n_in,
                              void* d_out, int out_size, void* d_ws, size_t ws_size,
                              hipStream_t stream) {
    const float* features = (const float*)d_in[0];
    const float* W1       = (const float*)d_in[1];
    const float* b1       = (const float*)d_in[2];
    const float* W2       = (const float*)d_in[3];
    const float* b2       = (const float*)d_in[4];
    const float* s_d      = (const float*)d_in[5];
    const int*   adj_row  = (const int*)d_in[6];
    const int*   adj_col  = (const int*)d_in[7];
    const int*   j_idx    = (const int*)d_in[9];
    float* out = (float*)d_out;

    const int N64 = N_NODES * 64;
    // Workspace layout:
    // zero region: [OVFACC N64 f][deg2in N f][cnt N int][ovf_cnt 16 int]
    // then: [dinv N f][dinv2 N f][A16 N64 us][B16 N64 us][h0 N*32 us][h1 N*32 us]
    //       [pdot NE f][ebuf N*CAP int][ovf NE int]
    float* ws = (float*)d_ws;
    float* OVFACC  = ws;
    float* deg2in  = OVFACC + N64;
    int*   cnt     = (int*)(deg2in + N_NODES);
    int*   ovf_cnt = cnt + N_NODES;
    float* dinv    = (float*)(ovf_cnt + 16);
    float* dinv2   = dinv + N_NODES;
    unsigned short* A16 = (unsigned short*)(dinv2 + N_NODES);
    unsigned short* B16 = A16 + N64;
    unsigned short* H0  = B16 + N64;      // N*32
    unsigned short* H1  = H0 + N_NODES * 32;
    float* pdot    = (float*)(H1 + N_NODES * 32);
    int*   ebuf    = (int*)(pdot + NE);
    int*   ovf     = ebuf + N_NODES * CAP;

    // Re-init (ws is poisoned 0xAA before every call)
    size_t zero_bytes = (size_t)(N64 + N_NODES + N_NODES + 16) * 4;
    hipMemsetAsync(OVFACC, 0, zero_bytes, stream);

    // Bucket adjacency by destination (also produces degree counts)
    k_scatter<<<(NE + 255) / 256, 256, 0, stream>>>(adj_row, adj_col, cnt, ebuf, ovf, ovf_cnt);
    k_dinv<<<(N_NODES + 255) / 256, 256, 0, stream>>>(cnt, dinv);

    // Layer 1: A16 = X@W1 ; B16 = relu(agg(A16) + dinv^2*A16 + b1)
    k_gemm<float><<<N_NODES / 32, 256, 0, stream>>>(features, W1, A16);
    k_ovf<<<16, 256, 0, stream>>>(A16, OVFACC, dinv, ovf, ovf_cnt, adj_row, adj_col);
    k_aggf<true, false><<<(N_NODES * 64) / 256, 256, 0, stream>>>(A16, B16, nullptr, OVFACC, dinv, cnt, ebuf, b1);

    // Re-zero overflow accumulator for layer 2 (stream-ordered after aggf1)
    hipMemsetAsync(OVFACC, 0, (size_t)N64 * 4, stream);

    // Layer 2: A16 = B16@W2 ; (H0|H1) = normalize(agg(A16) + dinv^2*A16 + b2)
    k_gemm<unsigned short><<<N_NODES / 32, 256, 0, stream>>>(B16, W2, A16);
    k_ovf<<<16, 256, 0, stream>>>(A16, OVFACC, dinv, ovf, ovf_cnt, adj_row, adj_col);
    k_aggf<false, true><<<(N_NODES * 64) / 256, 256, 0, stream>>>(A16, H0, H1, OVFACC, dinv, cnt, ebuf, b2);

    // Edge scores: half-0 partial dots, then half-1 + symmetrize
    float* outS = out + 2 * NE;
    k_dot0<<<NE * 8 / 256, 256, 0, stream>>>((const uint2*)H0, j_idx, pdot);
    k_edgesym2<<<NE * 8 / 256, 256, 0, stream>>>((const uint2*)H1, pdot, s_d, j_idx, outS, deg2in);
    k_dinv2<<<(N_NODES + 255) / 256, 256, 0, stream>>>(outS, deg2in, dinv2);

    // Final: vals_norm = out[0..2E)
    k_norm<<<2 * NE / 256, 256, 0, stream>>>(outS, dinv2, j_idx, out);
}

// Round 6
// 323.632 us; speedup vs baseline: 2.6507x; 1.0049x over previous
//
#include <hip/hip_runtime.h>

// Problem constants (match reference)
#define N_NODES 40000
#define ISIZE   64
#define KNN     24
#define NE      (N_NODES * KNN)      // 960000 edges (= E_ADJ as well)
#define OMEGA   0.9f
#define CAP     64                   // per-node bucket capacity (max deg ~46)
#define NBUCK   80                   // destination buckets of 512 nodes (c>>9)
#define LBUCK   10                   // buckets per XCD (NBUCK/8)
#define BCAP    16384                // edges per bucket capacity (mean 12288, +37 sigma)
#define EPT     8                    // edges per thread in k_bin
#define PBCH    512                  // edges per block in k_scatter2

// ---- bf16 helpers (storage-only precision; all math in fp32) -------------
__device__ __forceinline__ float bf2f(unsigned short s) {
    return __uint_as_float(((unsigned)s) << 16);
}
__device__ __forceinline__ unsigned short f2bf(float f) {  // round-nearest-even
    unsigned u = __float_as_uint(f);
    u += 0x7fffu + ((u >> 16) & 1u);
    return (unsigned short)(u >> 16);
}
__device__ __forceinline__ float bflo(unsigned u) { return __uint_as_float(u << 16); }
__device__ __forceinline__ float bfhi(unsigned u) { return __uint_as_float(u & 0xffff0000u); }
__device__ __forceinline__ float ldf(float x) { return x; }
__device__ __forceinline__ float ldf(unsigned short x) { return bf2f(x); }

// ---- pass 1: bin edges by destination range, packed (r<<16)|c ------------
__global__ void k_bin(const int* __restrict__ row, const int* __restrict__ col,
                      int* __restrict__ bcnt, unsigned* __restrict__ bbuf,
                      unsigned* __restrict__ ovf2, int* __restrict__ ovf2_cnt) {
    __shared__ int lcnt[NBUCK];
    __shared__ int lbase[NBUCK];
    int tid = threadIdx.x;
    for (int b = tid; b < NBUCK; b += 256) lcnt[b] = 0;
    __syncthreads();
    int e0 = blockIdx.x * (256 * EPT);
    int myslot[EPT]; int myb[EPT]; unsigned myp[EPT];
    for (int k = 0; k < EPT; k++) {
        int e = e0 + k * 256 + tid;
        if (e < NE) {
            int r = row[e], c = col[e];
            int b = c >> 9;
            myb[k] = b;
            myp[k] = ((unsigned)r << 16) | (unsigned)c;
            myslot[k] = atomicAdd(&lcnt[b], 1);
        } else myb[k] = -1;
    }
    __syncthreads();
    for (int b = tid; b < NBUCK; b += 256)
        lbase[b] = (lcnt[b] > 0) ? atomicAdd(&bcnt[b], lcnt[b]) : 0;
    __syncthreads();
    for (int k = 0; k < EPT; k++) {
        if (myb[k] < 0) continue;
        int pos = lbase[myb[k]] + myslot[k];
        if (pos < BCAP) bbuf[myb[k] * BCAP + pos] = myp[k];
        else { int p = atomicAdd(ovf2_cnt, 1); ovf2[p] = myp[k]; }
    }
}

// ---- pass 2: XCD-affine scatter into ebuf; cnt[] ends up as the degree ---
__global__ void k_scatter2(const unsigned* __restrict__ bbuf, const int* __restrict__ bcnt,
                           int* __restrict__ cnt, int* __restrict__ ebuf,
                           unsigned* __restrict__ ovf, int* __restrict__ ovf_cnt) {
    int xcd = blockIdx.x & 7;
    int t   = blockIdx.x >> 3;
    int lb  = t % LBUCK;
    int chunk = t / LBUCK;                 // 0..BCAP/PBCH-1
    int b = xcd + 8 * lb;                  // bucket; b%8==xcd for L2 locality
    int n = min(bcnt[b], BCAP);
    int start = chunk * PBCH;
    if (start >= n) return;
    int end = min(start + PBCH, n);
    for (int idx = start + threadIdx.x; idx < end; idx += 256) {
        unsigned p = bbuf[b * BCAP + idx];
        int c = (int)(p & 0xffffu), r = (int)(p >> 16);
        int slot = atomicAdd(&cnt[c], 1);
        if (slot < CAP) ebuf[c * CAP + slot] = r;
        else { int q = atomicAdd(ovf_cnt, 1); ovf[q] = p; }
    }
}

// ---- bin-overflow fallback (normally 0 edges) ----------------------------
__global__ void k_scat_ovf(const unsigned* __restrict__ ovf2, const int* __restrict__ ovf2_cnt,
                           int* __restrict__ cnt, int* __restrict__ ebuf,
                           unsigned* __restrict__ ovf, int* __restrict__ ovf_cnt) {
    int m = ovf2_cnt[0];
    for (int t = blockIdx.x * 256 + threadIdx.x; t < m; t += gridDim.x * 256) {
        unsigned p = ovf2[t];
        int c = (int)(p & 0xffffu), r = (int)(p >> 16);
        int slot = atomicAdd(&cnt[c], 1);
        if (slot < CAP) ebuf[c * CAP + slot] = r;
        else { int q = atomicAdd(ovf_cnt, 1); ovf[q] = p; }
    }
}

__global__ void k_dinv(const int* __restrict__ cnt, float* __restrict__ dinv) {
    int n = blockIdx.x * 256 + threadIdx.x;
    if (n < N_NODES) dinv[n] = rsqrtf(1.0f + (float)cnt[n]);
}

// ---- CAP-overflow fallback (normally 0): ovfacc[c] += dinv[r]*xw[r] ------
__global__ void k_ovf(const unsigned short* __restrict__ X0, const unsigned short* __restrict__ X1,
                      float* __restrict__ ovfacc, const float* __restrict__ dinv,
                      const unsigned* __restrict__ ovf, const int* __restrict__ ovf_cnt) {
    int total = ovf_cnt[0] * 64;
    for (int t = blockIdx.x * 256 + threadIdx.x; t < total; t += gridDim.x * 256) {
        unsigned p = ovf[t >> 6];
        int f = t & 63;
        int c = (int)(p & 0xffffu), r = (int)(p >> 16);
        float x = (f < 32) ? bf2f(X0[r * 32 + f]) : bf2f(X1[r * 32 + f - 32]);
        atomicAdd(&ovfacc[c * 64 + f], dinv[r] * x);
    }
}

// ---- Y = X @ W  (N x 64) * (64 x 64), bf16 split-half output -------------
template<typename T>
__global__ void k_gemm(const T* __restrict__ X, const float* __restrict__ W,
                       unsigned short* __restrict__ Y0, unsigned short* __restrict__ Y1) {
    __shared__ float sW[64 * 64];
    __shared__ float sX[32 * 64];
    int row0 = blockIdx.x * 32;
    for (int t = threadIdx.x; t < 64 * 64; t += 256) sW[t] = W[t];
    for (int t = threadIdx.x; t < 32 * 64; t += 256) sX[t] = ldf(X[row0 * 64 + t]);
    __syncthreads();
    int col = threadIdx.x & 63;
    int rl  = threadIdx.x >> 6;           // 0..3
    for (int r = rl; r < 32; r += 4) {
        float acc = 0.0f;
#pragma unroll
        for (int kk = 0; kk < 64; kk++) acc += sX[r * 64 + kk] * sW[kk * 64 + col];
        if (col < 32) Y0[(row0 + r) * 32 + col]      = f2bf(acc);
        else          Y1[(row0 + r) * 32 + col - 32] = f2bf(acc);
    }
}

// ---- pull aggregation, one wave per TWO nodes, phased half-gathers -------
// Phase A gathers only from X0 (2.56 MB, per-XCD-L2-resident), phase B from X1.
template<bool RELU, bool NORM>
__global__ void k_aggf2(const unsigned short* __restrict__ X0, const unsigned short* __restrict__ X1,
                        unsigned short* __restrict__ outF,     // full rows (layer 1)
                        unsigned short* __restrict__ O0,       // split (layer 2)
                        unsigned short* __restrict__ O1,
                        const float* __restrict__ ovfacc,
                        const float* __restrict__ dinv, const int* __restrict__ cnt,
                        const int* __restrict__ ebuf, const float* __restrict__ bias) {
    int w = (blockIdx.x * 256 + threadIdx.x) >> 6;   // wave id, 2 nodes/wave
    int lane = threadIdx.x & 63;
    int half = lane >> 5, sl = lane & 31;
    int n = w * 2 + half;
    if (n >= N_NODES) return;                        // n uniform per 32-lane half
    int deg = cnt[n];
    int bucketed = min(deg, CAP);
    int nb0 = min(bucketed, 32);
    int nb1 = bucketed - nb0;

    int   r0v = 0, r1v = 0;
    float d0v = 0.0f, d1v = 0.0f;
    if (sl < nb0) { r0v = ebuf[n * CAP + sl];      d0v = dinv[r0v]; }
    if (sl < nb1) { r1v = ebuf[n * CAP + 32 + sl]; d1v = dinv[r1v]; }

    float acc0 = ovfacc[n * 64 + sl];
    float acc1 = ovfacc[n * 64 + 32 + sl];

    // Phase A: features 0..31 from X0
    {
        int d = 0;
        for (; d + 3 < nb0; d += 4) {
            int   ra = __shfl(r0v, d, 32),     rb = __shfl(r0v, d + 1, 32);
            int   rc = __shfl(r0v, d + 2, 32), rd = __shfl(r0v, d + 3, 32);
            float ca = __shfl(d0v, d, 32),     cb = __shfl(d0v, d + 1, 32);
            float cc = __shfl(d0v, d + 2, 32), cd = __shfl(d0v, d + 3, 32);
            acc0 += ca * bf2f(X0[ra * 32 + sl]) + cb * bf2f(X0[rb * 32 + sl])
                  + cc * bf2f(X0[rc * 32 + sl]) + cd * bf2f(X0[rd * 32 + sl]);
        }
        for (; d < nb0; d++)
            acc0 += __shfl(d0v, d, 32) * bf2f(X0[__shfl(r0v, d, 32) * 32 + sl]);
        for (d = 0; d < nb1; d++)
            acc0 += __shfl(d1v, d, 32) * bf2f(X0[__shfl(r1v, d, 32) * 32 + sl]);
    }
    // Phase B: features 32..63 from X1
    {
        int d = 0;
        for (; d + 3 < nb0; d += 4) {
            int   ra = __shfl(r0v, d, 32),     rb = __shfl(r0v, d + 1, 32);
            int   rc = __shfl(r0v, d + 2, 32), rd = __shfl(r0v, d + 3, 32);
            float ca = __shfl(d0v, d, 32),     cb = __shfl(d0v, d + 1, 32);
            float cc = __shfl(d0v, d + 2, 32), cd = __shfl(d0v, d + 3, 32);
            acc1 += ca * bf2f(X1[ra * 32 + sl]) + cb * bf2f(X1[rb * 32 + sl])
                  + cc * bf2f(X1[rc * 32 + sl]) + cd * bf2f(X1[rd * 32 + sl]);
        }
        for (; d < nb0; d++)
            acc1 += __shfl(d0v, d, 32) * bf2f(X1[__shfl(r0v, d, 32) * 32 + sl]);
        for (d = 0; d < nb1; d++)
            acc1 += __shfl(d1v, d, 32) * bf2f(X1[__shfl(r1v, d, 32) * 32 + sl]);
    }

    float di = dinv[n];
    float v0 = di * acc0 + di * di * bf2f(X0[n * 32 + sl]) + bias[sl];
    float v1 = di * acc1 + di * di * bf2f(X1[n * 32 + sl]) + bias[32 + sl];
    if (RELU) { v0 = fmaxf(v0, 0.0f); v1 = fmaxf(v1, 0.0f); }
    if (NORM) {
        float s = v0 * v0 + v1 * v1;
#pragma unroll
        for (int m = 1; m < 32; m <<= 1) s += __shfl_xor(s, m, 32);
        float inv = 1.0f / fmaxf(sqrtf(s), 1e-12f);
        v0 *= inv; v1 *= inv;
    }
    if (NORM) {
        O0[n * 32 + sl] = f2bf(v0);
        O1[n * 32 + sl] = f2bf(v1);
    } else {
        outF[n * 64 + sl]      = f2bf(v0);
        outF[n * 64 + 32 + sl] = f2bf(v1);
    }
}

// ---- pass A: partial dot over feature half 0 (h0 = 2.56 MB, L2-resident) -
__global__ void k_dot0(const uint2* __restrict__ h0b, const int* __restrict__ j_idx,
                       float* __restrict__ pdot) {
    int t = blockIdx.x * 256 + threadIdx.x;   // NE*8 threads
    int e = t >> 3;
    int q = t & 7;
    int i = e / KNN;
    int j = j_idx[e];
    uint2 a = h0b[i * 8 + q];
    uint2 b = h0b[j * 8 + q];
    float s = bflo(a.x) * bflo(b.x) + bfhi(a.x) * bfhi(b.x)
            + bflo(a.y) * bflo(b.y) + bfhi(a.y) * bfhi(b.y);
    s += __shfl_xor(s, 1);
    s += __shfl_xor(s, 2);
    s += __shfl_xor(s, 4);
    if (q == 0) pdot[e] = s;
}

// ---- pass B: half 1 dot + reverse-match scan + symmetrize ----------------
__global__ void k_edgesym2(const uint2* __restrict__ h1b, const float* __restrict__ pdot,
                           const float* __restrict__ s_d, const int* __restrict__ j_idx,
                           float* __restrict__ outS,     // d_out + 2E, holds vals_s [2E]
                           float* __restrict__ deg2in) {
    int t = blockIdx.x * 256 + threadIdx.x;   // NE*8 threads
    int e = t >> 3;
    int q = t & 7;
    int i = e / KNN;
    int j = j_idx[e];
    uint2 a = h1b[i * 8 + q];
    uint2 b = h1b[j * 8 + q];
    float s = bflo(a.x) * bflo(b.x) + bfhi(a.x) * bfhi(b.x)
            + bflo(a.y) * bflo(b.y) + bfhi(a.y) * bfhi(b.y);

    // scan node j's 24-edge slice for j_idx == i (min index wins); 8 lanes x 3
    const int* jj = j_idx + j * KNN;
    int rt = 0x7fffffff;
    if (jj[q] == i) rt = q;
    if (jj[8 + q] == i) rt = min(rt, 8 + q);
    if (jj[16 + q] == i) rt = min(rt, 16 + q);

#pragma unroll
    for (int m = 1; m < 8; m <<= 1) {
        s  += __shfl_xor(s, m);
        rt  = min(rt, __shfl_xor(rt, m));
    }
    if (q == 0) {
        s += pdot[e];
        float base = OMEGA * fmaxf(s, 0.0f);
        float v, v2;
        if (rt != 0x7fffffff) {              // reverse edge exists (rare)
            int rev = j * KNN + rt;
            v  = base + 0.5f * (1.0f - OMEGA) * (s_d[e] + s_d[rev]);
            v2 = 0.0f;
        } else {
            v  = base + (1.0f - OMEGA) * s_d[e];
            v2 = v;
        }
        outS[e] = v;
        outS[NE + e] = v2;
        if (v2 != 0.0f) atomicAdd(&deg2in[j], v2);
    }
}

// ---- dinv2: atomic-free out-edge segment sum + random in-edge part -------
__global__ void k_dinv2(const float* __restrict__ outS, const float* __restrict__ deg2in,
                        float* __restrict__ dinv2) {
    int n = blockIdx.x * 256 + threadIdx.x;
    if (n >= N_NODES) return;
    float d = deg2in[n];
    const float* p = outS + n * KNN;
#pragma unroll
    for (int q = 0; q < KNN; q++) d += p[q];
    dinv2[n] = (d > 0.0f) ? rsqrtf(fmaxf(d, 1e-12f)) : 0.0f;
}

// ---- final normalization: vals_norm = dinv2[r] * vals_s * dinv2[c] -------
__global__ void k_norm(const float* __restrict__ outS, const float* __restrict__ dinv2,
                       const int* __restrict__ j_idx, float* __restrict__ out) {
    int t = blockIdx.x * 256 + threadIdx.x;   // 2*NE threads
    int r, c;
    if (t < NE) { r = t / KNN; c = j_idx[t]; }
    else        { int e = t - NE; r = j_idx[e]; c = e / KNN; }
    out[t] = dinv2[r] * outS[t] * dinv2[c];
}

extern "C" void kernel_launch(void* const* d_in, const int* in_sizes, int n_in,
                              void* d_out, int out_size, void* d_ws, size_t ws_size,
                              hipStream_t stream) {
    const float* features = (const float*)d_in[0];
    const float* W1       = (const float*)d_in[1];
    const float* b1       = (const float*)d_in[2];
    const float* W2       = (const float*)d_in[3];
    const float* b2       = (const float*)d_in[4];
    const float* s_d      = (const float*)d_in[5];
    const int*   adj_row  = (const int*)d_in[6];
    const int*   adj_col  = (const int*)d_in[7];
    const int*   j_idx    = (const int*)d_in[9];
    float* out = (float*)d_out;

    const int N64 = N_NODES * 64;
    const int N32 = N_NODES * 32;
    // Workspace layout (4-byte words):
    // zero region: [OVFACC N64][deg2in N][cnt N][ovfcnts 16][bcnt NBUCK]
    // then: [dinv N][dinv2 N][A0 N32 us][A1 N32 us][B16 N64 us][H0 N32 us][H1 N32 us]
    //       [ebuf N*CAP int][ovf NE uint][bbuf NBUCK*BCAP uint][pdot NE f (aliases ovf2)]
    float* ws = (float*)d_ws;
    float* OVFACC  = ws;
    float* deg2in  = OVFACC + N64;
    int*   cnt     = (int*)(deg2in + N_NODES);
    int*   ovfcnts = cnt + N_NODES;          // [0]=CAP ovf, [8]=bin ovf
    int*   bcnt    = ovfcnts + 16;
    float* dinv    = (float*)(bcnt + NBUCK);
    float* dinv2   = dinv + N_NODES;
    unsigned short* A0  = (unsigned short*)(dinv2 + N_NODES);
    unsigned short* A1  = A0 + N32;
    unsigned short* B16 = A1 + N32;
    unsigned short* H0  = B16 + N64;
    unsigned short* H1  = H0 + N32;
    int*      ebuf = (int*)(H1 + N32);
    unsigned* ovf  = (unsigned*)(ebuf + N_NODES * CAP);
    unsigned* bbuf = ovf + NE;
    float*    pdot = (float*)(bbuf + NBUCK * BCAP);
    unsigned* ovf2 = (unsigned*)pdot;        // alias: ovf2 dies before pdot is born

    // Re-init (ws is poisoned 0xAA before every call)
    size_t zero_bytes = (size_t)(N64 + N_NODES + N_NODES + 16 + NBUCK) * 4;
    hipMemsetAsync(OVFACC, 0, zero_bytes, stream);

    // Two-pass binned scatter (produces ebuf buckets + cnt degrees)
    k_bin<<<(NE + 256 * EPT - 1) / (256 * EPT), 256, 0, stream>>>(adj_row, adj_col, bcnt, bbuf, ovf2, ovfcnts + 8);
    k_scatter2<<<8 * LBUCK * (BCAP / PBCH), 256, 0, stream>>>(bbuf, bcnt, cnt, ebuf, ovf, ovfcnts);
    k_scat_ovf<<<8, 256, 0, stream>>>(ovf2, ovfcnts + 8, cnt, ebuf, ovf, ovfcnts);
    k_dinv<<<(N_NODES + 255) / 256, 256, 0, stream>>>(cnt, dinv);

    // Layer 1: (A0|A1) = X@W1 ; B16 = relu(agg + self + b1)
    k_gemm<float><<<N_NODES / 32, 256, 0, stream>>>(features, W1, A0, A1);
    k_ovf<<<16, 256, 0, stream>>>(A0, A1, OVFACC, dinv, ovf, ovfcnts);
    k_aggf2<true, false><<<(N_NODES / 2 * 64 + 255) / 256, 256, 0, stream>>>(A0, A1, B16, nullptr, nullptr, OVFACC, dinv, cnt, ebuf, b1);

    // Re-zero overflow accumulator for layer 2 (stream-ordered after aggf1)
    hipMemsetAsync(OVFACC, 0, (size_t)N64 * 4, stream);

    // Layer 2: (A0|A1) = B16@W2 ; (H0|H1) = normalize(agg + self + b2)
    k_gemm<unsigned short><<<N_NODES / 32, 256, 0, stream>>>(B16, W2, A0, A1);
    k_ovf<<<16, 256, 0, stream>>>(A0, A1, OVFACC, dinv, ovf, ovfcnts);
    k_aggf2<false, true><<<(N_NODES / 2 * 64 + 255) / 256, 256, 0, stream>>>(A0, A1, nullptr, H0, H1, OVFACC, dinv, cnt, ebuf, b2);

    // Edge scores: half-0 partial dots, then half-1 + symmetrize
    float* outS = out + 2 * NE;
    k_dot0<<<NE * 8 / 256, 256, 0, stream>>>((const uint2*)H0, j_idx, pdot);
    k_edgesym2<<<NE * 8 / 256, 256, 0, stream>>>((const uint2*)H1, pdot, s_d, j_idx, outS, deg2in);
    k_dinv2<<<(N_NODES + 255) / 256, 256, 0, stream>>>(outS, deg2in, dinv2);

    // Final: vals_norm = out[0..2E)
    k_norm<<<2 * NE / 256, 256, 0, stream>>>(outS, dinv2, j_idx, out);
}